// Round 1
// 102.182 us; speedup vs baseline: 1.0792x; 1.0792x over previous
//
#include <hip/hip_runtime.h>

#define TT 512
#define DD 256
#define BB 2
#define MM (BB*TT)          // 1024
#define LCH 8               // wkv chunk length (R5: 16 -> 8, full-wave scan)
#define NCH (TT/LCH)        // 64 chunks per channel

// ---------------------------------------------------------------------------
// K1: k/v/r = timemix(X) @ W^T, stored TRANSPOSED as (B, D, T) for the scan.
// R5: 64(m)x64(n) tile, 256 threads (4 waves -> all 4 SIMDs of a CU busy),
// 192 blocks (single scheduling round on 256 CUs).  K-chunks of 32 with
// register prefetch + double-buffered LDS: next chunk's global loads are in
// flight while the current chunk's 512 FMAs run; one barrier per chunk.
// NOTE (R4 post-mortem): do NOT fuse stages with grid barriers — on MI355X
// the agent-scope fences cost ~50-70us in serialized L2 wb/inv.
// ---------------------------------------------------------------------------
__global__ __launch_bounds__(256)
void gemm_mix_t(const float* __restrict__ X, const float* __restrict__ Xlast,
                const float* __restrict__ W0, const float* __restrict__ W1,
                const float* __restrict__ W2,
                const float* __restrict__ mx0, const float* __restrict__ mx1,
                const float* __restrict__ mx2,
                float* __restrict__ O0, float* __restrict__ O1,
                float* __restrict__ O2)
{
    const int mat = blockIdx.z;
    const float* W  = (mat == 0) ? W0  : (mat == 1) ? W1  : W2;
    const float* mx = (mat == 0) ? mx0 : (mat == 1) ? mx1 : mx2;
    float*       O  = (mat == 0) ? O0  : (mat == 1) ? O1  : O2;

    const int n0  = blockIdx.x * 64;
    const int m0  = blockIdx.y * 64;
    const int b   = m0 / TT;
    const int t0  = m0 % TT;
    const int tid = threadIdx.x;

    // staging thread map: 8 lanes x 128B along k, 32 row-groups
    const int cc = (tid & 7) * 4;    // k offset within 32-chunk
    const int r8 = tid >> 3;         // 0..31 (row; rows r8 and r8+32)
    // compute thread map: 16x16 groups of 4x4
    const int tm = tid >> 4;         // 0..15 (m groups of 4)
    const int tn = tid & 15;         // 0..15 (n groups of 4)

    __shared__ float As[2][32][68];  // [buf][k][m], pad 68 keeps b128 16B-aligned
    __shared__ float Bs[2][32][68];  // [buf][k][n]

    float4 a0, a1, b0, b1;           // prefetch registers (mix already applied)

    auto load_chunk = [&](int k0) {
        const float4 mv = *(const float4*)&mx[k0 + cc];
        {
            const int rr  = r8;
            const int row = m0 + rr;
            const float4 xc = *(const float4*)&X[(size_t)row * DD + k0 + cc];
            float4 xp;
            if (t0 + rr == 0) xp = *(const float4*)&Xlast[b * DD + k0 + cc];
            else              xp = *(const float4*)&X[(size_t)(row - 1) * DD + k0 + cc];
            a0.x = xp.x + (xc.x - xp.x) * mv.x;
            a0.y = xp.y + (xc.y - xp.y) * mv.y;
            a0.z = xp.z + (xc.z - xp.z) * mv.z;
            a0.w = xp.w + (xc.w - xp.w) * mv.w;
            b0 = *(const float4*)&W[(size_t)(n0 + rr) * DD + k0 + cc];
        }
        {
            const int rr  = r8 + 32;
            const int row = m0 + rr;
            const float4 xc = *(const float4*)&X[(size_t)row * DD + k0 + cc];
            float4 xp;
            if (t0 + rr == 0) xp = *(const float4*)&Xlast[b * DD + k0 + cc];
            else              xp = *(const float4*)&X[(size_t)(row - 1) * DD + k0 + cc];
            a1.x = xp.x + (xc.x - xp.x) * mv.x;
            a1.y = xp.y + (xc.y - xp.y) * mv.y;
            a1.z = xp.z + (xc.z - xp.z) * mv.z;
            a1.w = xp.w + (xc.w - xp.w) * mv.w;
            b1 = *(const float4*)&W[(size_t)(n0 + rr) * DD + k0 + cc];
        }
    };

    float acc[4][4] = {};
    load_chunk(0);

    for (int c = 0; c < 8; ++c) {
        const int buf = c & 1;
        // drain prefetch regs into LDS (transpose to [k][m])
        As[buf][cc + 0][r8]      = a0.x; As[buf][cc + 1][r8]      = a0.y;
        As[buf][cc + 2][r8]      = a0.z; As[buf][cc + 3][r8]      = a0.w;
        As[buf][cc + 0][r8 + 32] = a1.x; As[buf][cc + 1][r8 + 32] = a1.y;
        As[buf][cc + 2][r8 + 32] = a1.z; As[buf][cc + 3][r8 + 32] = a1.w;
        Bs[buf][cc + 0][r8]      = b0.x; Bs[buf][cc + 1][r8]      = b0.y;
        Bs[buf][cc + 2][r8]      = b0.z; Bs[buf][cc + 3][r8]      = b0.w;
        Bs[buf][cc + 0][r8 + 32] = b1.x; Bs[buf][cc + 1][r8 + 32] = b1.y;
        Bs[buf][cc + 2][r8 + 32] = b1.z; Bs[buf][cc + 3][r8 + 32] = b1.w;
        // issue next chunk's global loads BEFORE the barrier: latency hides
        // under this chunk's FMAs (regs only, touches neither LDS buffer)
        if (c < 7) load_chunk((c + 1) * 32);
        __syncthreads();
        #pragma unroll
        for (int kk = 0; kk < 32; ++kk) {
            const float4 a4 = *(const float4*)&As[buf][kk][tm * 4];
            const float4 b4 = *(const float4*)&Bs[buf][kk][tn * 4];
            const float am[4] = {a4.x, a4.y, a4.z, a4.w};
            const float bn[4] = {b4.x, b4.y, b4.z, b4.w};
            #pragma unroll
            for (int i = 0; i < 4; ++i)
                #pragma unroll
                for (int j = 0; j < 4; ++j)
                    acc[i][j] = fmaf(am[i], bn[j], acc[i][j]);
        }
        // no second barrier: next iteration writes the OTHER buffer, and the
        // single barrier per iteration orders reuse two iterations apart.
    }

    // store transposed: O[(b, n, t)] ; t = t0 + tm*4 + i, n = n0 + tn*4 + j
    #pragma unroll
    for (int j = 0; j < 4; ++j) {
        const float4 o = make_float4(acc[0][j], acc[1][j], acc[2][j], acc[3][j]);
        *(float4*)&O[(size_t)(b * DD + n0 + tn * 4 + j) * TT + t0 + tm * 4] = o;
    }
}

// ---------------------------------------------------------------------------
// K2: WKV via chunked parallel scan.  R5: chunk L=8, one full 64-lane wave
// per channel (6 shfl rounds), 128 blocks x 256 thr (2x CU coverage, half
// the serial per-thread work of the L=16 version).
// ---------------------------------------------------------------------------
__global__ __launch_bounds__(256)
void wkv_scan(const float* __restrict__ kT, const float* __restrict__ vT,
              const float* __restrict__ rT, const float* __restrict__ x,
              const float* __restrict__ last_num, const float* __restrict__ last_den,
              const float* __restrict__ time_decay, const float* __restrict__ time_first,
              float* __restrict__ yT, float* __restrict__ out)
{
    const int tid  = threadIdx.x;
    const int ch   = blockIdx.x * 4 + (tid >> 6);
    const int lane = tid & 63;           // chunk index
    const int b    = ch >> 8;
    const int d    = ch & (DD - 1);

    const float w  = -__expf(time_decay[d]);
    const float ew = __expf(w);
    const float eu = __expf(time_first[d]);

    const size_t base = (size_t)ch * TT + lane * LCH;
    float k_[LCH], v_[LCH], r_[LCH];
    #pragma unroll
    for (int i = 0; i < LCH / 4; ++i) {
        *(float4*)&k_[4 * i] = *(const float4*)(kT + base + 4 * i);
        *(float4*)&v_[4 * i] = *(const float4*)(vT + base + 4 * i);
        *(float4*)&r_[4 * i] = *(const float4*)(rT + base + 4 * i);
    }

    float ek[LCH], ekv[LCH], sr[LCH];
    #pragma unroll
    for (int i = 0; i < LCH; ++i) {
        ek[i]  = __expf(k_[i]);
        ekv[i] = ek[i] * v_[i];
        sr[i]  = __builtin_amdgcn_rcpf(1.0f + __expf(-r_[i]));
    }

    float A = __expf(w * (float)LCH);
    float Bn = 0.0f, Bd = 0.0f;
    #pragma unroll
    for (int i = 0; i < LCH; ++i) {
        Bn = fmaf(ew, Bn, ekv[i]);
        Bd = fmaf(ew, Bd, ek[i]);
    }

    #pragma unroll
    for (int s = 1; s < 64; s <<= 1) {
        const float Ax  = __shfl_up(A, s, 64);
        const float Bnx = __shfl_up(Bn, s, 64);
        const float Bdx = __shfl_up(Bd, s, 64);
        if (lane >= s) {
            Bn = fmaf(A, Bnx, Bn);
            Bd = fmaf(A, Bdx, Bd);
            A *= Ax;
        }
    }

    float Aex  = __shfl_up(A, 1, 64);
    float Bnex = __shfl_up(Bn, 1, 64);
    float Bdex = __shfl_up(Bd, 1, 64);
    if (lane == 0) { Aex = 1.0f; Bnex = 0.0f; Bdex = 0.0f; }
    float sn = fmaf(Aex, last_num[ch], Bnex);
    float sd = fmaf(Aex, last_den[ch], Bdex);

    float y_[LCH];
    #pragma unroll
    for (int i = 0; i < LCH; ++i) {
        const float euk = eu * ek[i];
        const float wkv = (sn + eu * ekv[i]) * __builtin_amdgcn_rcpf(sd + euk);
        y_[i] = wkv * sr[i];
        sn = fmaf(ew, sn, ekv[i]);
        sd = fmaf(ew, sd, ek[i]);
    }
    #pragma unroll
    for (int i = 0; i < LCH / 4; ++i)
        *(float4*)(yT + base + 4 * i) = *(const float4*)&y_[4 * i];

    if (lane == 63) {
        out[MM * DD + BB * DD + ch]     = sn;
        out[MM * DD + 2 * BB * DD + ch] = sd;
    }
    if (lane == 0)
        out[MM * DD + ch] = x[(b * TT + TT - 1) * DD + d];
}

// ---------------------------------------------------------------------------
// K3: out = yT^T @ Wo^T.  R5: 32(t)x32(n) tile but 256 threads / 2x2 micro:
// 256 blocks x 4 waves = 1024 waves = one wave on EVERY SIMD of the chip
// (the old 64-thread version left 3 of 4 SIMDs per CU idle).  Same
// prefetch + double-buffer pipeline as K1, K-chunks of 64.
// ---------------------------------------------------------------------------
__global__ __launch_bounds__(256)
void gemm_out(const float* __restrict__ yT, const float* __restrict__ Wo,
              float* __restrict__ O)
{
    const int n0  = blockIdx.x * 32;
    const int m0  = blockIdx.y * 32;
    const int b   = m0 >> 9;            // /TT
    const int t0  = m0 & (TT - 1);
    const int tid = threadIdx.x;

    __shared__ float As[2][64][36];     // [buf][k][t]
    __shared__ float Bs[2][64][36];     // [buf][k][n]

    const int tm = tid >> 4;            // 0..15
    const int tn = tid & 15;            // 0..15

    const int kq  = tid >> 3;           // 0..31  (A stage: k)
    const int mq  = (tid & 7) * 4;      //        (A stage: t)
    const int cc  = (tid & 15) * 4;     // B stage: k
    const int r16 = tid >> 4;           // B stage: n row 0..15

    float4 av0, av1, wv0, wv1;
    auto load_chunk = [&](int k0) {
        av0 = *(const float4*)&yT[(size_t)(b * DD + k0 + kq) * TT + t0 + mq];
        av1 = *(const float4*)&yT[(size_t)(b * DD + k0 + kq + 32) * TT + t0 + mq];
        wv0 = *(const float4*)&Wo[(size_t)(n0 + r16) * DD + k0 + cc];
        wv1 = *(const float4*)&Wo[(size_t)(n0 + r16 + 16) * DD + k0 + cc];
    };

    float acc[2][2] = {};
    load_chunk(0);

    for (int c = 0; c < 4; ++c) {
        const int buf = c & 1;
        // A comes pre-transposed (D,T): direct b128 LDS rows
        *(float4*)&As[buf][kq][mq]      = av0;
        *(float4*)&As[buf][kq + 32][mq] = av1;
        // B: transpose Wo rows into [k][n]
        Bs[buf][cc + 0][r16]      = wv0.x; Bs[buf][cc + 1][r16]      = wv0.y;
        Bs[buf][cc + 2][r16]      = wv0.z; Bs[buf][cc + 3][r16]      = wv0.w;
        Bs[buf][cc + 0][r16 + 16] = wv1.x; Bs[buf][cc + 1][r16 + 16] = wv1.y;
        Bs[buf][cc + 2][r16 + 16] = wv1.z; Bs[buf][cc + 3][r16 + 16] = wv1.w;
        if (c < 3) load_chunk((c + 1) * 64);
        __syncthreads();
        #pragma unroll
        for (int kk = 0; kk < 64; ++kk) {
            const float2 a2 = *(const float2*)&As[buf][kk][tm * 2];
            const float2 b2 = *(const float2*)&Bs[buf][kk][tn * 2];
            acc[0][0] = fmaf(a2.x, b2.x, acc[0][0]);
            acc[0][1] = fmaf(a2.x, b2.y, acc[0][1]);
            acc[1][0] = fmaf(a2.y, b2.x, acc[1][0]);
            acc[1][1] = fmaf(a2.y, b2.y, acc[1][1]);
        }
    }

    #pragma unroll
    for (int i = 0; i < 2; ++i) {
        const float2 o = make_float2(acc[i][0], acc[i][1]);
        *(float2*)&O[(size_t)(m0 + tm * 2 + i) * DD + n0 + tn * 2] = o;
    }
}

// ---------------------------------------------------------------------------
extern "C" void kernel_launch(void* const* d_in, const int* in_sizes, int n_in,
                              void* d_out, int out_size, void* d_ws, size_t ws_size,
                              hipStream_t stream)
{
    const float* x    = (const float*)d_in[0];
    const float* lx   = (const float*)d_in[1];
    const float* lnum = (const float*)d_in[2];
    const float* lden = (const float*)d_in[3];
    const float* td   = (const float*)d_in[4];
    const float* tf   = (const float*)d_in[5];
    const float* mk   = (const float*)d_in[6];
    const float* mv   = (const float*)d_in[7];
    const float* mr   = (const float*)d_in[8];
    const float* Wk   = (const float*)d_in[9];
    const float* Wv   = (const float*)d_in[10];
    const float* Wr   = (const float*)d_in[11];
    const float* Wo   = (const float*)d_in[12];
    float* out = (float*)d_out;

    float* kT = (float*)d_ws;          // (B, D, T)
    float* vT = kT + MM * DD;
    float* rT = vT + MM * DD;          // raw r (sigmoid applied in K2)
    float* yT = rT + MM * DD;          // (B, D, T) = wkv * sigmoid(r)

    gemm_mix_t<<<dim3(4, 16, 3), 256, 0, stream>>>(
        x, lx, Wk, Wv, Wr, mk, mv, mr, kT, vT, rT);

    wkv_scan<<<dim3(128), 256, 0, stream>>>(
        kT, vT, rT, x, lnum, lden, td, tf, yT, out);

    gemm_out<<<dim3(8, 32), 256, 0, stream>>>(yT, Wo, out);
}

// Round 2
// 101.268 us; speedup vs baseline: 1.0889x; 1.0090x over previous
//
#include <hip/hip_runtime.h>

#define TT 512
#define DD 256
#define BB 2
#define MM (BB*TT)          // 1024
#define LCH 8               // wkv chunk length (full-wave scan)

// ---------------------------------------------------------------------------
// K1: k/v/r = timemix(X) @ W^T, stored TRANSPOSED as (B, D, T) for the scan.
// R6: LDS-pipe-bound analysis -> spread over ALL CUs: 768 one-wave blocks
// (32x32 tile, 4x4 micro).  Single-wave blocks need NO barriers (one
// instruction stream orders LDS RAW/WAR by itself); double-buffered LDS +
// register prefetch hides global (L2) latency under the 512-FMA chunk.
// Reads As[kk][tm*4]: banks (4kk+4tm)%32 -> 8 distinct quads, conflict-free.
// NOTE (R4 post-mortem): do NOT fuse stages with grid barriers — agent-scope
// fences cost ~50-70us on MI355X.
// ---------------------------------------------------------------------------
__global__ __launch_bounds__(64)
void gemm_mix_t(const float* __restrict__ X, const float* __restrict__ Xlast,
                const float* __restrict__ W0, const float* __restrict__ W1,
                const float* __restrict__ W2,
                const float* __restrict__ mx0, const float* __restrict__ mx1,
                const float* __restrict__ mx2,
                float* __restrict__ O0, float* __restrict__ O1,
                float* __restrict__ O2)
{
    const int mat = blockIdx.z;
    const float* W  = (mat == 0) ? W0  : (mat == 1) ? W1  : W2;
    const float* mx = (mat == 0) ? mx0 : (mat == 1) ? mx1 : mx2;
    float*       O  = (mat == 0) ? O0  : (mat == 1) ? O1  : O2;

    const int n0   = blockIdx.x * 32;
    const int m0   = blockIdx.y * 32;
    const int b    = m0 / TT;
    const int t0   = m0 % TT;
    const int lane = threadIdx.x;

    const int cc = (lane & 7) * 4;   // k offset within 32-chunk (staging)
    const int g  = lane >> 3;        // 0..7 row group (staging)
    const int tm = lane >> 3;        // 0..7 (m groups of 4, compute)
    const int tn = lane & 7;         // 0..7 (n groups of 4, compute)

    __shared__ float As[2][32][36];  // [buf][k][m] pad 36: reads clean, writes 4-way
    __shared__ float Bs[2][32][36];  // [buf][k][n]

    float4 a[4], w4[4];              // prefetch regs (mix already applied)

    auto load_chunk = [&](int k0) {
        const float4 mv = *(const float4*)&mx[k0 + cc];
        #pragma unroll
        for (int i = 0; i < 4; ++i) {
            const int rr  = g + 8 * i;
            const int row = m0 + rr;
            const float4 xc = *(const float4*)&X[(size_t)row * DD + k0 + cc];
            float4 xp;
            if (t0 + rr == 0) xp = *(const float4*)&Xlast[b * DD + k0 + cc];
            else              xp = *(const float4*)&X[(size_t)(row - 1) * DD + k0 + cc];
            a[i].x = xp.x + (xc.x - xp.x) * mv.x;
            a[i].y = xp.y + (xc.y - xp.y) * mv.y;
            a[i].z = xp.z + (xc.z - xp.z) * mv.z;
            a[i].w = xp.w + (xc.w - xp.w) * mv.w;
            w4[i] = *(const float4*)&W[(size_t)(n0 + rr) * DD + k0 + cc];
        }
    };

    float acc[4][4] = {};
    load_chunk(0);

    for (int c = 0; c < 8; ++c) {
        const int buf = c & 1;
        // drain prefetch regs into LDS (transpose to [k][m]/[k][n])
        #pragma unroll
        for (int i = 0; i < 4; ++i) {
            const int rr = g + 8 * i;
            As[buf][cc + 0][rr] = a[i].x; As[buf][cc + 1][rr] = a[i].y;
            As[buf][cc + 2][rr] = a[i].z; As[buf][cc + 3][rr] = a[i].w;
            Bs[buf][cc + 0][rr] = w4[i].x; Bs[buf][cc + 1][rr] = w4[i].y;
            Bs[buf][cc + 2][rr] = w4[i].z; Bs[buf][cc + 3][rr] = w4[i].w;
        }
        // issue next chunk's global loads; latency hides under the FMAs
        if (c < 7) load_chunk((c + 1) * 32);
        // no __syncthreads: single wave, program order covers LDS deps
        #pragma unroll
        for (int kk = 0; kk < 32; ++kk) {
            const float4 a4 = *(const float4*)&As[buf][kk][tm * 4];
            const float4 b4 = *(const float4*)&Bs[buf][kk][tn * 4];
            const float am[4] = {a4.x, a4.y, a4.z, a4.w};
            const float bn[4] = {b4.x, b4.y, b4.z, b4.w};
            #pragma unroll
            for (int i = 0; i < 4; ++i)
                #pragma unroll
                for (int j = 0; j < 4; ++j)
                    acc[i][j] = fmaf(am[i], bn[j], acc[i][j]);
        }
    }

    // store transposed: O[(b, n, t)] ; t = t0 + tm*4 + i, n = n0 + tn*4 + j
    #pragma unroll
    for (int j = 0; j < 4; ++j) {
        const float4 o = make_float4(acc[0][j], acc[1][j], acc[2][j], acc[3][j]);
        *(float4*)&O[(size_t)(b * DD + n0 + tn * 4 + j) * TT + t0 + tm * 4] = o;
    }
}

// ---------------------------------------------------------------------------
// K2: WKV via chunked parallel scan, L=8, one 64-lane wave per channel.
// R6: 256 blocks x 128 thr (2 channels/block) -> all 256 CUs on this
// BW-bound kernel (16 MB traffic, ~2.5us floor).
// ---------------------------------------------------------------------------
__global__ __launch_bounds__(128)
void wkv_scan(const float* __restrict__ kT, const float* __restrict__ vT,
              const float* __restrict__ rT, const float* __restrict__ x,
              const float* __restrict__ last_num, const float* __restrict__ last_den,
              const float* __restrict__ time_decay, const float* __restrict__ time_first,
              float* __restrict__ yT, float* __restrict__ out)
{
    const int tid  = threadIdx.x;
    const int ch   = blockIdx.x * 2 + (tid >> 6);
    const int lane = tid & 63;           // chunk index
    const int b    = ch >> 8;
    const int d    = ch & (DD - 1);

    const float w  = -__expf(time_decay[d]);
    const float ew = __expf(w);
    const float eu = __expf(time_first[d]);

    const size_t base = (size_t)ch * TT + lane * LCH;
    float k_[LCH], v_[LCH], r_[LCH];
    #pragma unroll
    for (int i = 0; i < LCH / 4; ++i) {
        *(float4*)&k_[4 * i] = *(const float4*)(kT + base + 4 * i);
        *(float4*)&v_[4 * i] = *(const float4*)(vT + base + 4 * i);
        *(float4*)&r_[4 * i] = *(const float4*)(rT + base + 4 * i);
    }

    float ek[LCH], ekv[LCH], sr[LCH];
    #pragma unroll
    for (int i = 0; i < LCH; ++i) {
        ek[i]  = __expf(k_[i]);
        ekv[i] = ek[i] * v_[i];
        sr[i]  = __builtin_amdgcn_rcpf(1.0f + __expf(-r_[i]));
    }

    float A = __expf(w * (float)LCH);
    float Bn = 0.0f, Bd = 0.0f;
    #pragma unroll
    for (int i = 0; i < LCH; ++i) {
        Bn = fmaf(ew, Bn, ekv[i]);
        Bd = fmaf(ew, Bd, ek[i]);
    }

    #pragma unroll
    for (int s = 1; s < 64; s <<= 1) {
        const float Ax  = __shfl_up(A, s, 64);
        const float Bnx = __shfl_up(Bn, s, 64);
        const float Bdx = __shfl_up(Bd, s, 64);
        if (lane >= s) {
            Bn = fmaf(A, Bnx, Bn);
            Bd = fmaf(A, Bdx, Bd);
            A *= Ax;
        }
    }

    float Aex  = __shfl_up(A, 1, 64);
    float Bnex = __shfl_up(Bn, 1, 64);
    float Bdex = __shfl_up(Bd, 1, 64);
    if (lane == 0) { Aex = 1.0f; Bnex = 0.0f; Bdex = 0.0f; }
    float sn = fmaf(Aex, last_num[ch], Bnex);
    float sd = fmaf(Aex, last_den[ch], Bdex);

    float y_[LCH];
    #pragma unroll
    for (int i = 0; i < LCH; ++i) {
        const float euk = eu * ek[i];
        const float wkv = (sn + eu * ekv[i]) * __builtin_amdgcn_rcpf(sd + euk);
        y_[i] = wkv * sr[i];
        sn = fmaf(ew, sn, ekv[i]);
        sd = fmaf(ew, sd, ek[i]);
    }
    #pragma unroll
    for (int i = 0; i < LCH / 4; ++i)
        *(float4*)(yT + base + 4 * i) = *(const float4*)&y_[4 * i];

    if (lane == 63) {
        out[MM * DD + BB * DD + ch]     = sn;
        out[MM * DD + 2 * BB * DD + ch] = sd;
    }
    if (lane == 0)
        out[MM * DD + ch] = x[(b * TT + TT - 1) * DD + d];
}

// ---------------------------------------------------------------------------
// K3: out = yT^T @ Wo^T.  R6: K-split across 2 waves.  256 blocks x 128 thr,
// 32x32 tile, 4x4 micro; wave w owns k in [w*128, w*128+128) with wave-
// PRIVATE LDS (no barriers in the main loop).  A-stage is direct b128 rows
// (yT is (D,T)); pad 40 makes writes 2-way (free) and reads conflict-free.
// One __syncthreads at the end for the cross-wave acc reduction.
// ---------------------------------------------------------------------------
__global__ __launch_bounds__(128)
void gemm_out(const float* __restrict__ yT, const float* __restrict__ Wo,
              float* __restrict__ O)
{
    const int n0   = blockIdx.x * 32;
    const int m0   = blockIdx.y * 32;
    const int b    = m0 >> 9;           // /TT
    const int t0   = m0 & (TT - 1);
    const int tid  = threadIdx.x;
    const int wv   = tid >> 6;          // 0,1: K-half owner
    const int lane = tid & 63;

    __shared__ float As[2][32][40];     // [wave][k][t] pad 40 (b128 writes 2-way)
    __shared__ float Bs[2][32][36];     // [wave][k][n] pad 36

    const int tm = lane >> 3;           // 0..7
    const int tn = lane & 7;            // 0..7
    const int kr = lane >> 3;           // A stage: k row group
    const int mq = (lane & 7) * 4;      // A stage: t
    const int cc = (lane & 7) * 4;      // B stage: k
    const int g  = lane >> 3;           // B stage: n row group

    const int kbase = wv * 128;

    float4 av[4], wv4[4];
    auto load_chunk = [&](int k0) {
        #pragma unroll
        for (int i = 0; i < 4; ++i)
            av[i] = *(const float4*)&yT[(size_t)(b * DD + k0 + kr + 8 * i) * TT + t0 + mq];
        #pragma unroll
        for (int i = 0; i < 4; ++i)
            wv4[i] = *(const float4*)&Wo[(size_t)(n0 + g + 8 * i) * DD + k0 + cc];
    };

    float acc[4][4] = {};
    load_chunk(kbase);

    for (int c = 0; c < 4; ++c) {
        // stage A: direct b128 rows into wave-private buffer
        #pragma unroll
        for (int i = 0; i < 4; ++i)
            *(float4*)&As[wv][kr + 8 * i][mq] = av[i];
        // stage B: transpose Wo rows into [k][n]
        #pragma unroll
        for (int i = 0; i < 4; ++i) {
            const int rr = g + 8 * i;
            Bs[wv][cc + 0][rr] = wv4[i].x; Bs[wv][cc + 1][rr] = wv4[i].y;
            Bs[wv][cc + 2][rr] = wv4[i].z; Bs[wv][cc + 3][rr] = wv4[i].w;
        }
        if (c < 3) load_chunk(kbase + (c + 1) * 32);
        // no barrier: each wave reads only its own LDS region
        #pragma unroll
        for (int kk = 0; kk < 32; ++kk) {
            const float4 a4 = *(const float4*)&As[wv][kk][tm * 4];
            const float4 b4 = *(const float4*)&Bs[wv][kk][tn * 4];
            const float am[4] = {a4.x, a4.y, a4.z, a4.w};
            const float bn[4] = {b4.x, b4.y, b4.z, b4.w};
            #pragma unroll
            for (int i = 0; i < 4; ++i)
                #pragma unroll
                for (int j = 0; j < 4; ++j)
                    acc[i][j] = fmaf(am[i], bn[j], acc[i][j]);
        }
    }

    // cross-wave K reduction: wave1 parks its acc in its own (now dead) A
    // buffer (32*40 = 1280 floats >= 64*20), wave0 adds and stores.
    float* red = &As[1][0][0];
    if (wv == 1) {
        #pragma unroll
        for (int i = 0; i < 4; ++i)
            *(float4*)&red[lane * 20 + i * 4] =
                make_float4(acc[i][0], acc[i][1], acc[i][2], acc[i][3]);
    }
    __syncthreads();
    if (wv == 0) {
        #pragma unroll
        for (int i = 0; i < 4; ++i) {
            const float4 o = *(const float4*)&red[lane * 20 + i * 4];
            acc[i][0] += o.x; acc[i][1] += o.y;
            acc[i][2] += o.z; acc[i][3] += o.w;
        }
        #pragma unroll
        for (int i = 0; i < 4; ++i)
            *(float4*)&O[(size_t)(m0 + tm * 4 + i) * DD + n0 + tn * 4] =
                make_float4(acc[i][0], acc[i][1], acc[i][2], acc[i][3]);
    }
}

// ---------------------------------------------------------------------------
extern "C" void kernel_launch(void* const* d_in, const int* in_sizes, int n_in,
                              void* d_out, int out_size, void* d_ws, size_t ws_size,
                              hipStream_t stream)
{
    const float* x    = (const float*)d_in[0];
    const float* lx   = (const float*)d_in[1];
    const float* lnum = (const float*)d_in[2];
    const float* lden = (const float*)d_in[3];
    const float* td   = (const float*)d_in[4];
    const float* tf   = (const float*)d_in[5];
    const float* mk   = (const float*)d_in[6];
    const float* mv   = (const float*)d_in[7];
    const float* mr   = (const float*)d_in[8];
    const float* Wk   = (const float*)d_in[9];
    const float* Wv   = (const float*)d_in[10];
    const float* Wr   = (const float*)d_in[11];
    const float* Wo   = (const float*)d_in[12];
    float* out = (float*)d_out;

    float* kT = (float*)d_ws;          // (B, D, T)
    float* vT = kT + MM * DD;
    float* rT = vT + MM * DD;          // raw r (sigmoid applied in K2)
    float* yT = rT + MM * DD;          // (B, D, T) = wkv * sigmoid(r)

    gemm_mix_t<<<dim3(8, 32, 3), 64, 0, stream>>>(
        x, lx, Wk, Wv, Wr, mk, mv, mr, kT, vT, rT);

    wkv_scan<<<dim3(256), 128, 0, stream>>>(
        kT, vT, rT, x, lnum, lden, td, tf, yT, out);

    gemm_out<<<dim3(8, 32), 128, 0, stream>>>(yT, Wo, out);
}

// Round 3
// 99.114 us; speedup vs baseline: 1.1126x; 1.0217x over previous
//
#include <hip/hip_runtime.h>

#define TT 512
#define DD 256
#define BB 2
#define MM (BB*TT)          // 1024
#define LCH 8               // wkv chunk length (full-wave scan)

// ---------------------------------------------------------------------------
// K1: k/v/r = timemix(X) @ W^T, stored TRANSPOSED as (B, D, T).
// R7: VALU-makespan fix.  768 blocks x 256 thr; each block = 32x32 tile,
// K SPLIT 4 WAYS across waves (wave w owns k in [w*64, w*64+64)).
// 12 waves/CU = 3/SIMD on all 4 SIMDs -> even FMA makespan (~6144 cyc vs
// 8192 with 3 one-wave blocks).  Wave-private single-buffer LDS: same-wave
// program order covers RAW/WAR, NO barriers in the main loop; register
// prefetch still hides global latency under the FMA block.  One barrier
// for the cross-wave acc reduction.
// NOTE (R4 post-mortem): do NOT fuse stages with grid barriers — agent-scope
// fences cost ~50-70us on MI355X.
// ---------------------------------------------------------------------------
__global__ __launch_bounds__(256)
void gemm_mix_t(const float* __restrict__ X, const float* __restrict__ Xlast,
                const float* __restrict__ W0, const float* __restrict__ W1,
                const float* __restrict__ W2,
                const float* __restrict__ mx0, const float* __restrict__ mx1,
                const float* __restrict__ mx2,
                float* __restrict__ O0, float* __restrict__ O1,
                float* __restrict__ O2)
{
    const int mat = blockIdx.z;
    const float* W  = (mat == 0) ? W0  : (mat == 1) ? W1  : W2;
    const float* mx = (mat == 0) ? mx0 : (mat == 1) ? mx1 : mx2;
    float*       O  = (mat == 0) ? O0  : (mat == 1) ? O1  : O2;

    const int n0   = blockIdx.x * 32;
    const int m0   = blockIdx.y * 32;
    const int b    = m0 / TT;
    const int t0   = m0 % TT;
    const int tid  = threadIdx.x;
    const int wv   = tid >> 6;       // 0..3: K-quarter owner
    const int lane = tid & 63;

    const int cc = (lane & 7) * 4;   // k offset within 32-chunk (staging)
    const int g  = lane >> 3;        // 0..7 row group (staging)
    const int tm = lane >> 3;        // 0..7 (m groups of 4, compute)
    const int tn = lane & 7;         // 0..7 (n groups of 4, compute)

    __shared__ float As[4][32][36];  // [wave][k][m] pad 36 (reads clean, writes 4-way)
    __shared__ float Bs[4][32][36];  // [wave][k][n]

    const int kb = wv * 64;

    float4 a[4], w4[4];              // prefetch regs (mix already applied)
    auto load_chunk = [&](int k0) {
        const float4 mv = *(const float4*)&mx[k0 + cc];
        #pragma unroll
        for (int i = 0; i < 4; ++i) {
            const int rr  = g + 8 * i;
            const int row = m0 + rr;
            const float4 xc = *(const float4*)&X[(size_t)row * DD + k0 + cc];
            float4 xp;
            if (t0 + rr == 0) xp = *(const float4*)&Xlast[b * DD + k0 + cc];
            else              xp = *(const float4*)&X[(size_t)(row - 1) * DD + k0 + cc];
            a[i].x = xp.x + (xc.x - xp.x) * mv.x;
            a[i].y = xp.y + (xc.y - xp.y) * mv.y;
            a[i].z = xp.z + (xc.z - xp.z) * mv.z;
            a[i].w = xp.w + (xc.w - xp.w) * mv.w;
            w4[i] = *(const float4*)&W[(size_t)(n0 + rr) * DD + k0 + cc];
        }
    };

    float acc[4][4] = {};
    load_chunk(kb);

    #pragma unroll
    for (int c = 0; c < 2; ++c) {
        // drain prefetch regs into wave-private LDS (transpose to [k][*])
        #pragma unroll
        for (int i = 0; i < 4; ++i) {
            const int rr = g + 8 * i;
            As[wv][cc + 0][rr] = a[i].x; As[wv][cc + 1][rr] = a[i].y;
            As[wv][cc + 2][rr] = a[i].z; As[wv][cc + 3][rr] = a[i].w;
            Bs[wv][cc + 0][rr] = w4[i].x; Bs[wv][cc + 1][rr] = w4[i].y;
            Bs[wv][cc + 2][rr] = w4[i].z; Bs[wv][cc + 3][rr] = w4[i].w;
        }
        if (c == 0) load_chunk(kb + 32);
        // no barrier: wave-private buffer, program order covers LDS deps
        #pragma unroll
        for (int kk = 0; kk < 32; ++kk) {
            const float4 a4 = *(const float4*)&As[wv][kk][tm * 4];
            const float4 b4 = *(const float4*)&Bs[wv][kk][tn * 4];
            const float am[4] = {a4.x, a4.y, a4.z, a4.w};
            const float bn[4] = {b4.x, b4.y, b4.z, b4.w};
            #pragma unroll
            for (int i = 0; i < 4; ++i)
                #pragma unroll
                for (int j = 0; j < 4; ++j)
                    acc[i][j] = fmaf(am[i], bn[j], acc[i][j]);
        }
    }

    // cross-wave K reduction: waves 1..3 park accs in their (dead) A buffers
    if (wv != 0) {
        float* park = &As[wv][0][0];            // 1152 floats >= 1024
        #pragma unroll
        for (int i = 0; i < 4; ++i)
            *(float4*)&park[(i * 64 + lane) * 4] =
                make_float4(acc[i][0], acc[i][1], acc[i][2], acc[i][3]);
    }
    __syncthreads();
    if (wv == 0) {
        #pragma unroll
        for (int w = 1; w < 4; ++w) {
            const float* park = &As[w][0][0];
            #pragma unroll
            for (int i = 0; i < 4; ++i) {
                const float4 o = *(const float4*)&park[(i * 64 + lane) * 4];
                acc[i][0] += o.x; acc[i][1] += o.y;
                acc[i][2] += o.z; acc[i][3] += o.w;
            }
        }
        // store transposed: O[(b, n, t)] ; t = t0+tm*4+i, n = n0+tn*4+j
        #pragma unroll
        for (int j = 0; j < 4; ++j) {
            const float4 o = make_float4(acc[0][j], acc[1][j], acc[2][j], acc[3][j]);
            *(float4*)&O[(size_t)(b * DD + n0 + tn * 4 + j) * TT + t0 + tm * 4] = o;
        }
    }
}

// ---------------------------------------------------------------------------
// K2: WKV via chunked parallel scan, L=8, one 64-lane wave per channel.
// 256 blocks x 128 thr (2 channels/block) -> all 256 CUs.
// ---------------------------------------------------------------------------
__global__ __launch_bounds__(128)
void wkv_scan(const float* __restrict__ kT, const float* __restrict__ vT,
              const float* __restrict__ rT, const float* __restrict__ x,
              const float* __restrict__ last_num, const float* __restrict__ last_den,
              const float* __restrict__ time_decay, const float* __restrict__ time_first,
              float* __restrict__ yT, float* __restrict__ out)
{
    const int tid  = threadIdx.x;
    const int ch   = blockIdx.x * 2 + (tid >> 6);
    const int lane = tid & 63;           // chunk index
    const int b    = ch >> 8;
    const int d    = ch & (DD - 1);

    const float w  = -__expf(time_decay[d]);
    const float ew = __expf(w);
    const float eu = __expf(time_first[d]);

    const size_t base = (size_t)ch * TT + lane * LCH;
    float k_[LCH], v_[LCH], r_[LCH];
    #pragma unroll
    for (int i = 0; i < LCH / 4; ++i) {
        *(float4*)&k_[4 * i] = *(const float4*)(kT + base + 4 * i);
        *(float4*)&v_[4 * i] = *(const float4*)(vT + base + 4 * i);
        *(float4*)&r_[4 * i] = *(const float4*)(rT + base + 4 * i);
    }

    float ek[LCH], ekv[LCH], sr[LCH];
    #pragma unroll
    for (int i = 0; i < LCH; ++i) {
        ek[i]  = __expf(k_[i]);
        ekv[i] = ek[i] * v_[i];
        sr[i]  = __builtin_amdgcn_rcpf(1.0f + __expf(-r_[i]));
    }

    float A = __expf(w * (float)LCH);
    float Bn = 0.0f, Bd = 0.0f;
    #pragma unroll
    for (int i = 0; i < LCH; ++i) {
        Bn = fmaf(ew, Bn, ekv[i]);
        Bd = fmaf(ew, Bd, ek[i]);
    }

    #pragma unroll
    for (int s = 1; s < 64; s <<= 1) {
        const float Ax  = __shfl_up(A, s, 64);
        const float Bnx = __shfl_up(Bn, s, 64);
        const float Bdx = __shfl_up(Bd, s, 64);
        if (lane >= s) {
            Bn = fmaf(A, Bnx, Bn);
            Bd = fmaf(A, Bdx, Bd);
            A *= Ax;
        }
    }

    float Aex  = __shfl_up(A, 1, 64);
    float Bnex = __shfl_up(Bn, 1, 64);
    float Bdex = __shfl_up(Bd, 1, 64);
    if (lane == 0) { Aex = 1.0f; Bnex = 0.0f; Bdex = 0.0f; }
    float sn = fmaf(Aex, last_num[ch], Bnex);
    float sd = fmaf(Aex, last_den[ch], Bdex);

    float y_[LCH];
    #pragma unroll
    for (int i = 0; i < LCH; ++i) {
        const float euk = eu * ek[i];
        const float wkv = (sn + eu * ekv[i]) * __builtin_amdgcn_rcpf(sd + euk);
        y_[i] = wkv * sr[i];
        sn = fmaf(ew, sn, ekv[i]);
        sd = fmaf(ew, sd, ek[i]);
    }
    #pragma unroll
    for (int i = 0; i < LCH / 4; ++i)
        *(float4*)(yT + base + 4 * i) = *(const float4*)&y_[4 * i];

    if (lane == 63) {
        out[MM * DD + BB * DD + ch]     = sn;
        out[MM * DD + 2 * BB * DD + ch] = sd;
    }
    if (lane == 0)
        out[MM * DD + ch] = x[(b * TT + TT - 1) * DD + d];
}

// ---------------------------------------------------------------------------
// K3: out = yT^T @ Wo^T.  R7: K split 4 ways (wave w owns k in [w*64,+64)),
// 256 blocks x 256 thr = 4 waves on every CU -> FMA makespan 2048 cyc
// (was 4096 on 2 of 4 SIMDs).  Wave-private double-buffered LDS, no
// barriers in the main loop; one barrier for the acc reduction.
// ---------------------------------------------------------------------------
__global__ __launch_bounds__(256)
void gemm_out(const float* __restrict__ yT, const float* __restrict__ Wo,
              float* __restrict__ O)
{
    const int n0   = blockIdx.x * 32;
    const int m0   = blockIdx.y * 32;
    const int b    = m0 >> 9;           // /TT
    const int t0   = m0 & (TT - 1);
    const int tid  = threadIdx.x;
    const int wv   = tid >> 6;          // 0..3: K-quarter owner
    const int lane = tid & 63;

    __shared__ float As[4][2][32][40];  // [wave][buf][k][t] pad 40 (b128 writes 2-way)
    __shared__ float Bs[4][2][32][36];  // [wave][buf][k][n] pad 36

    const int tm = lane >> 3;           // 0..7
    const int tn = lane & 7;            // 0..7
    const int kr = lane >> 3;           // A stage: k row group
    const int mq = (lane & 7) * 4;      // A stage: t
    const int cc = (lane & 7) * 4;      // B stage: k
    const int g  = lane >> 3;           // B stage: n row group

    const int kb = wv * 64;

    float4 av[4], wv4[4];
    auto load_chunk = [&](int k0) {
        #pragma unroll
        for (int i = 0; i < 4; ++i)
            av[i] = *(const float4*)&yT[(size_t)(b * DD + k0 + kr + 8 * i) * TT + t0 + mq];
        #pragma unroll
        for (int i = 0; i < 4; ++i)
            wv4[i] = *(const float4*)&Wo[(size_t)(n0 + g + 8 * i) * DD + k0 + cc];
    };

    float acc[4][4] = {};
    load_chunk(kb);

    #pragma unroll
    for (int c = 0; c < 2; ++c) {
        const int buf = c & 1;
        // stage A: direct b128 rows (yT is (D,T)) into wave-private buffer
        #pragma unroll
        for (int i = 0; i < 4; ++i)
            *(float4*)&As[wv][buf][kr + 8 * i][mq] = av[i];
        // stage B: transpose Wo rows into [k][n]
        #pragma unroll
        for (int i = 0; i < 4; ++i) {
            const int rr = g + 8 * i;
            Bs[wv][buf][cc + 0][rr] = wv4[i].x; Bs[wv][buf][cc + 1][rr] = wv4[i].y;
            Bs[wv][buf][cc + 2][rr] = wv4[i].z; Bs[wv][buf][cc + 3][rr] = wv4[i].w;
        }
        if (c == 0) load_chunk(kb + 32);
        // no barrier: wave-private
        #pragma unroll
        for (int kk = 0; kk < 32; ++kk) {
            const float4 a4 = *(const float4*)&As[wv][buf][kk][tm * 4];
            const float4 b4 = *(const float4*)&Bs[wv][buf][kk][tn * 4];
            const float am[4] = {a4.x, a4.y, a4.z, a4.w};
            const float bn[4] = {b4.x, b4.y, b4.z, b4.w};
            #pragma unroll
            for (int i = 0; i < 4; ++i)
                #pragma unroll
                for (int j = 0; j < 4; ++j)
                    acc[i][j] = fmaf(am[i], bn[j], acc[i][j]);
        }
    }

    // cross-wave K reduction: waves 1..3 park accs (stride 20 -> conflict-free)
    if (wv != 0) {
        float* park = &As[wv][0][0][0];         // 2560 floats >= 64*20
        #pragma unroll
        for (int i = 0; i < 4; ++i)
            *(float4*)&park[lane * 20 + i * 4] =
                make_float4(acc[i][0], acc[i][1], acc[i][2], acc[i][3]);
    }
    __syncthreads();
    if (wv == 0) {
        #pragma unroll
        for (int w = 1; w < 4; ++w) {
            const float* park = &As[w][0][0][0];
            #pragma unroll
            for (int i = 0; i < 4; ++i) {
                const float4 o = *(const float4*)&park[lane * 20 + i * 4];
                acc[i][0] += o.x; acc[i][1] += o.y;
                acc[i][2] += o.z; acc[i][3] += o.w;
            }
        }
        #pragma unroll
        for (int i = 0; i < 4; ++i)
            *(float4*)&O[(size_t)(m0 + tm * 4 + i) * DD + n0 + tn * 4] =
                make_float4(acc[i][0], acc[i][1], acc[i][2], acc[i][3]);
    }
}

// ---------------------------------------------------------------------------
extern "C" void kernel_launch(void* const* d_in, const int* in_sizes, int n_in,
                              void* d_out, int out_size, void* d_ws, size_t ws_size,
                              hipStream_t stream)
{
    const float* x    = (const float*)d_in[0];
    const float* lx   = (const float*)d_in[1];
    const float* lnum = (const float*)d_in[2];
    const float* lden = (const float*)d_in[3];
    const float* td   = (const float*)d_in[4];
    const float* tf   = (const float*)d_in[5];
    const float* mk   = (const float*)d_in[6];
    const float* mv   = (const float*)d_in[7];
    const float* mr   = (const float*)d_in[8];
    const float* Wk   = (const float*)d_in[9];
    const float* Wv   = (const float*)d_in[10];
    const float* Wr   = (const float*)d_in[11];
    const float* Wo   = (const float*)d_in[12];
    float* out = (float*)d_out;

    float* kT = (float*)d_ws;          // (B, D, T)
    float* vT = kT + MM * DD;
    float* rT = vT + MM * DD;          // raw r (sigmoid applied in K2)
    float* yT = rT + MM * DD;          // (B, D, T) = wkv * sigmoid(r)

    gemm_mix_t<<<dim3(8, 32, 3), 256, 0, stream>>>(
        x, lx, Wk, Wv, Wr, mk, mv, mr, kT, vT, rT);

    wkv_scan<<<dim3(256), 128, 0, stream>>>(
        kT, vT, rT, x, lnum, lden, td, tf, yT, out);

    gemm_out<<<dim3(8, 32), 256, 0, stream>>>(yT, Wo, out);
}

// Round 4
// 96.565 us; speedup vs baseline: 1.1420x; 1.0264x over previous
//
#include <hip/hip_runtime.h>

#define TT 512
#define DD 256
#define BB 2
#define MM (BB*TT)          // 1024

// v_pk_fma_f32: 2 fp32 FMAs per instruction (VOP3P).  op_sel broadcasts the
// A-operand scalar: PK_LO uses a.lo in both halves, PK_HI uses a.hi.
// Arithmetic is bit-identical to the scalar fmaf pair (IEEE fma per half).
#define PK_LO(acc, a, b) \
    asm("v_pk_fma_f32 %0, %1, %2, %0 op_sel:[0,0,0] op_sel_hi:[0,1,1]" \
        : "+v"(acc) : "v"(a), "v"(b))
#define PK_HI(acc, a, b) \
    asm("v_pk_fma_f32 %0, %1, %2, %0 op_sel:[1,0,0] op_sel_hi:[1,1,1]" \
        : "+v"(acc) : "v"(a), "v"(b))

// ---------------------------------------------------------------------------
// K1: k/v/r = timemix(X) @ W^T, stored TRANSPOSED as (B, D, T).
// R8: same R7 structure (768 blocks x 4 waves, wave-private K-quarter,
// no-barrier main loop) but the 16-FMA micro-kernel is 8 v_pk_fma_f32 —
// tests whether gfx950 packed fp32 halves VALU issue (MI250X-style) or is
// issue-neutral (MI300X-style).  Bit-identical accumulation either way.
// NOTE (R4 post-mortem): do NOT fuse stages with grid barriers — agent-scope
// fences cost ~50-70us on MI355X.
// ---------------------------------------------------------------------------
__global__ __launch_bounds__(256)
void gemm_mix_t(const float* __restrict__ X, const float* __restrict__ Xlast,
                const float* __restrict__ W0, const float* __restrict__ W1,
                const float* __restrict__ W2,
                const float* __restrict__ mx0, const float* __restrict__ mx1,
                const float* __restrict__ mx2,
                float* __restrict__ O0, float* __restrict__ O1,
                float* __restrict__ O2)
{
    const int mat = blockIdx.z;
    const float* W  = (mat == 0) ? W0  : (mat == 1) ? W1  : W2;
    const float* mx = (mat == 0) ? mx0 : (mat == 1) ? mx1 : mx2;
    float*       O  = (mat == 0) ? O0  : (mat == 1) ? O1  : O2;

    const int n0   = blockIdx.x * 32;
    const int m0   = blockIdx.y * 32;
    const int b    = m0 / TT;
    const int t0   = m0 % TT;
    const int tid  = threadIdx.x;
    const int wv   = tid >> 6;       // 0..3: K-quarter owner
    const int lane = tid & 63;

    const int cc = (lane & 7) * 4;   // k offset within 32-chunk (staging)
    const int g  = lane >> 3;        // 0..7 row group (staging)
    const int tm = lane >> 3;        // 0..7 (m groups of 4, compute)
    const int tn = lane & 7;         // 0..7 (n groups of 4, compute)

    __shared__ float As[4][32][36];  // [wave][k][m] pad 36
    __shared__ float Bs[4][32][36];  // [wave][k][n]

    const int kb = wv * 64;

    float4 a[4], w4[4];              // prefetch regs (mix already applied)
    auto load_chunk = [&](int k0) {
        const float4 mv = *(const float4*)&mx[k0 + cc];
        #pragma unroll
        for (int i = 0; i < 4; ++i) {
            const int rr  = g + 8 * i;
            const int row = m0 + rr;
            const float4 xc = *(const float4*)&X[(size_t)row * DD + k0 + cc];
            float4 xp;
            if (t0 + rr == 0) xp = *(const float4*)&Xlast[b * DD + k0 + cc];
            else              xp = *(const float4*)&X[(size_t)(row - 1) * DD + k0 + cc];
            a[i].x = xp.x + (xc.x - xp.x) * mv.x;
            a[i].y = xp.y + (xc.y - xp.y) * mv.y;
            a[i].z = xp.z + (xc.z - xp.z) * mv.z;
            a[i].w = xp.w + (xc.w - xp.w) * mv.w;
            w4[i] = *(const float4*)&W[(size_t)(n0 + rr) * DD + k0 + cc];
        }
    };

    float2 acc2[4][2] = {};          // [i][jp]: (acc[i][2jp], acc[i][2jp+1])
    load_chunk(kb);

    #pragma unroll
    for (int c = 0; c < 2; ++c) {
        #pragma unroll
        for (int i = 0; i < 4; ++i) {
            const int rr = g + 8 * i;
            As[wv][cc + 0][rr] = a[i].x; As[wv][cc + 1][rr] = a[i].y;
            As[wv][cc + 2][rr] = a[i].z; As[wv][cc + 3][rr] = a[i].w;
            Bs[wv][cc + 0][rr] = w4[i].x; Bs[wv][cc + 1][rr] = w4[i].y;
            Bs[wv][cc + 2][rr] = w4[i].z; Bs[wv][cc + 3][rr] = w4[i].w;
        }
        if (c == 0) load_chunk(kb + 32);
        // no barrier: wave-private buffer, program order covers LDS deps
        #pragma unroll
        for (int kk = 0; kk < 32; ++kk) {
            const float2 a01 = *(const float2*)&As[wv][kk][tm * 4];
            const float2 a23 = *(const float2*)&As[wv][kk][tm * 4 + 2];
            const float2 b01 = *(const float2*)&Bs[wv][kk][tn * 4];
            const float2 b23 = *(const float2*)&Bs[wv][kk][tn * 4 + 2];
            PK_LO(acc2[0][0], a01, b01); PK_LO(acc2[0][1], a01, b23);
            PK_HI(acc2[1][0], a01, b01); PK_HI(acc2[1][1], a01, b23);
            PK_LO(acc2[2][0], a23, b01); PK_LO(acc2[2][1], a23, b23);
            PK_HI(acc2[3][0], a23, b01); PK_HI(acc2[3][1], a23, b23);
        }
    }

    // cross-wave K reduction: waves 1..3 park accs in their (dead) A buffers
    if (wv != 0) {
        float* park = &As[wv][0][0];            // 1152 floats >= 1024
        #pragma unroll
        for (int i = 0; i < 4; ++i)
            *(float4*)&park[(i * 64 + lane) * 4] =
                make_float4(acc2[i][0].x, acc2[i][0].y, acc2[i][1].x, acc2[i][1].y);
    }
    __syncthreads();
    if (wv == 0) {
        #pragma unroll
        for (int w = 1; w < 4; ++w) {
            const float* park = &As[w][0][0];
            #pragma unroll
            for (int i = 0; i < 4; ++i) {
                const float4 o = *(const float4*)&park[(i * 64 + lane) * 4];
                acc2[i][0].x += o.x; acc2[i][0].y += o.y;
                acc2[i][1].x += o.z; acc2[i][1].y += o.w;
            }
        }
        // store transposed: O[(b, n, t)] ; t = t0+tm*4+i, n = n0+tn*4+j
        const float4 oj0 = make_float4(acc2[0][0].x, acc2[1][0].x, acc2[2][0].x, acc2[3][0].x);
        const float4 oj1 = make_float4(acc2[0][0].y, acc2[1][0].y, acc2[2][0].y, acc2[3][0].y);
        const float4 oj2 = make_float4(acc2[0][1].x, acc2[1][1].x, acc2[2][1].x, acc2[3][1].x);
        const float4 oj3 = make_float4(acc2[0][1].y, acc2[1][1].y, acc2[2][1].y, acc2[3][1].y);
        *(float4*)&O[(size_t)(b * DD + n0 + tn * 4 + 0) * TT + t0 + tm * 4] = oj0;
        *(float4*)&O[(size_t)(b * DD + n0 + tn * 4 + 1) * TT + t0 + tm * 4] = oj1;
        *(float4*)&O[(size_t)(b * DD + n0 + tn * 4 + 2) * TT + t0 + tm * 4] = oj2;
        *(float4*)&O[(size_t)(b * DD + n0 + tn * 4 + 3) * TT + t0 + tm * 4] = oj3;
    }
}

// ---------------------------------------------------------------------------
// K2: WKV parallel scan.  R8: each channel split across 2 waves (L=4,
// half-T per wave); wave1 composes wave0's segment total via a 3-float LDS
// handoff + one barrier.  256 blocks x 256 thr = 4 waves on all 4 SIMDs of
// every CU (was 2), and per-thread serial work halved.
// ---------------------------------------------------------------------------
__global__ __launch_bounds__(256)
void wkv_scan(const float* __restrict__ kT, const float* __restrict__ vT,
              const float* __restrict__ rT, const float* __restrict__ x,
              const float* __restrict__ last_num, const float* __restrict__ last_den,
              const float* __restrict__ time_decay, const float* __restrict__ time_first,
              float* __restrict__ yT, float* __restrict__ out)
{
    const int tid  = threadIdx.x;
    const int chl  = tid >> 7;           // 0..1 channel within block
    const int half = (tid >> 6) & 1;     // 0..1 T-half owner
    const int lane = tid & 63;
    const int ch   = blockIdx.x * 2 + chl;
    const int b    = ch >> 8;
    const int d    = ch & (DD - 1);

    const float w  = -__expf(time_decay[d]);
    const float ew = __expf(w);
    const float eu = __expf(time_first[d]);

    const size_t base = (size_t)ch * TT + half * (TT / 2) + lane * 4;
    const float4 k4 = *(const float4*)(kT + base);
    const float4 v4 = *(const float4*)(vT + base);
    const float4 r4 = *(const float4*)(rT + base);
    const float k_[4] = {k4.x, k4.y, k4.z, k4.w};
    const float v_[4] = {v4.x, v4.y, v4.z, v4.w};
    const float r_[4] = {r4.x, r4.y, r4.z, r4.w};

    float ek[4], ekv[4], sr[4];
    #pragma unroll
    for (int i = 0; i < 4; ++i) {
        ek[i]  = __expf(k_[i]);
        ekv[i] = ek[i] * v_[i];
        sr[i]  = __builtin_amdgcn_rcpf(1.0f + __expf(-r_[i]));
    }

    float A = __expf(w * 4.0f);
    float Bn = 0.0f, Bd = 0.0f;
    #pragma unroll
    for (int i = 0; i < 4; ++i) {
        Bn = fmaf(ew, Bn, ekv[i]);
        Bd = fmaf(ew, Bd, ek[i]);
    }

    #pragma unroll
    for (int s = 1; s < 64; s <<= 1) {
        const float Ax  = __shfl_up(A, s, 64);
        const float Bnx = __shfl_up(Bn, s, 64);
        const float Bdx = __shfl_up(Bd, s, 64);
        if (lane >= s) {
            Bn = fmaf(A, Bnx, Bn);
            Bd = fmaf(A, Bdx, Bd);
            A *= Ax;
        }
    }

    // publish wave0's half-total (inclusive at lane 63) for wave1
    __shared__ float h[2][3];
    if (half == 0 && lane == 63) { h[chl][0] = A; h[chl][1] = Bn; h[chl][2] = Bd; }

    float Aex  = __shfl_up(A, 1, 64);
    float Bnex = __shfl_up(Bn, 1, 64);
    float Bdex = __shfl_up(Bd, 1, 64);
    if (lane == 0) { Aex = 1.0f; Bnex = 0.0f; Bdex = 0.0f; }

    __syncthreads();

    float s0n = last_num[ch], s0d = last_den[ch];
    if (half == 1) {
        s0n = fmaf(h[chl][0], s0n, h[chl][1]);
        s0d = fmaf(h[chl][0], s0d, h[chl][2]);
    }
    float sn = fmaf(Aex, s0n, Bnex);
    float sd = fmaf(Aex, s0d, Bdex);

    float y_[4];
    #pragma unroll
    for (int i = 0; i < 4; ++i) {
        const float euk = eu * ek[i];
        const float wkv = (sn + eu * ekv[i]) * __builtin_amdgcn_rcpf(sd + euk);
        y_[i] = wkv * sr[i];
        sn = fmaf(ew, sn, ekv[i]);
        sd = fmaf(ew, sd, ek[i]);
    }
    *(float4*)(yT + base) = make_float4(y_[0], y_[1], y_[2], y_[3]);

    if (half == 1 && lane == 63) {
        out[MM * DD + BB * DD + ch]     = sn;
        out[MM * DD + 2 * BB * DD + ch] = sd;
    }
    if (half == 0 && lane == 0)
        out[MM * DD + ch] = x[(b * TT + TT - 1) * DD + d];
}

// ---------------------------------------------------------------------------
// K3: out = yT^T @ Wo^T.  R7 structure (4-way K-split, wave-private dbuf,
// no main-loop barrier) + R8 pk_fma micro-kernel.
// ---------------------------------------------------------------------------
__global__ __launch_bounds__(256)
void gemm_out(const float* __restrict__ yT, const float* __restrict__ Wo,
              float* __restrict__ O)
{
    const int n0   = blockIdx.x * 32;
    const int m0   = blockIdx.y * 32;
    const int b    = m0 >> 9;           // /TT
    const int t0   = m0 & (TT - 1);
    const int tid  = threadIdx.x;
    const int wv   = tid >> 6;          // 0..3: K-quarter owner
    const int lane = tid & 63;

    __shared__ float As[4][2][32][40];  // [wave][buf][k][t] pad 40
    __shared__ float Bs[4][2][32][36];  // [wave][buf][k][n] pad 36

    const int tm = lane >> 3;           // 0..7
    const int tn = lane & 7;            // 0..7
    const int kr = lane >> 3;           // A stage: k row group
    const int mq = (lane & 7) * 4;      // A stage: t
    const int cc = (lane & 7) * 4;      // B stage: k
    const int g  = lane >> 3;           // B stage: n row group

    const int kb = wv * 64;

    float4 av[4], wv4[4];
    auto load_chunk = [&](int k0) {
        #pragma unroll
        for (int i = 0; i < 4; ++i)
            av[i] = *(const float4*)&yT[(size_t)(b * DD + k0 + kr + 8 * i) * TT + t0 + mq];
        #pragma unroll
        for (int i = 0; i < 4; ++i)
            wv4[i] = *(const float4*)&Wo[(size_t)(n0 + g + 8 * i) * DD + k0 + cc];
    };

    float2 acc2[4][2] = {};
    load_chunk(kb);

    #pragma unroll
    for (int c = 0; c < 2; ++c) {
        const int buf = c & 1;
        #pragma unroll
        for (int i = 0; i < 4; ++i)
            *(float4*)&As[wv][buf][kr + 8 * i][mq] = av[i];
        #pragma unroll
        for (int i = 0; i < 4; ++i) {
            const int rr = g + 8 * i;
            Bs[wv][buf][cc + 0][rr] = wv4[i].x; Bs[wv][buf][cc + 1][rr] = wv4[i].y;
            Bs[wv][buf][cc + 2][rr] = wv4[i].z; Bs[wv][buf][cc + 3][rr] = wv4[i].w;
        }
        if (c == 0) load_chunk(kb + 32);
        // no barrier: wave-private
        #pragma unroll
        for (int kk = 0; kk < 32; ++kk) {
            const float2 a01 = *(const float2*)&As[wv][buf][kk][tm * 4];
            const float2 a23 = *(const float2*)&As[wv][buf][kk][tm * 4 + 2];
            const float2 b01 = *(const float2*)&Bs[wv][buf][kk][tn * 4];
            const float2 b23 = *(const float2*)&Bs[wv][buf][kk][tn * 4 + 2];
            PK_LO(acc2[0][0], a01, b01); PK_LO(acc2[0][1], a01, b23);
            PK_HI(acc2[1][0], a01, b01); PK_HI(acc2[1][1], a01, b23);
            PK_LO(acc2[2][0], a23, b01); PK_LO(acc2[2][1], a23, b23);
            PK_HI(acc2[3][0], a23, b01); PK_HI(acc2[3][1], a23, b23);
        }
    }

    // cross-wave K reduction: waves 1..3 park accs (stride 20 -> conflict-free)
    if (wv != 0) {
        float* park = &As[wv][0][0][0];         // 2560 floats >= 64*20
        #pragma unroll
        for (int i = 0; i < 4; ++i)
            *(float4*)&park[lane * 20 + i * 4] =
                make_float4(acc2[i][0].x, acc2[i][0].y, acc2[i][1].x, acc2[i][1].y);
    }
    __syncthreads();
    if (wv == 0) {
        #pragma unroll
        for (int w = 1; w < 4; ++w) {
            const float* park = &As[w][0][0][0];
            #pragma unroll
            for (int i = 0; i < 4; ++i) {
                const float4 o = *(const float4*)&park[lane * 20 + i * 4];
                acc2[i][0].x += o.x; acc2[i][0].y += o.y;
                acc2[i][1].x += o.z; acc2[i][1].y += o.w;
            }
        }
        #pragma unroll
        for (int i = 0; i < 4; ++i)
            *(float4*)&O[(size_t)(m0 + tm * 4 + i) * DD + n0 + tn * 4] =
                make_float4(acc2[i][0].x, acc2[i][0].y, acc2[i][1].x, acc2[i][1].y);
    }
}

// ---------------------------------------------------------------------------
extern "C" void kernel_launch(void* const* d_in, const int* in_sizes, int n_in,
                              void* d_out, int out_size, void* d_ws, size_t ws_size,
                              hipStream_t stream)
{
    const float* x    = (const float*)d_in[0];
    const float* lx   = (const float*)d_in[1];
    const float* lnum = (const float*)d_in[2];
    const float* lden = (const float*)d_in[3];
    const float* td   = (const float*)d_in[4];
    const float* tf   = (const float*)d_in[5];
    const float* mk   = (const float*)d_in[6];
    const float* mv   = (const float*)d_in[7];
    const float* mr   = (const float*)d_in[8];
    const float* Wk   = (const float*)d_in[9];
    const float* Wv   = (const float*)d_in[10];
    const float* Wr   = (const float*)d_in[11];
    const float* Wo   = (const float*)d_in[12];
    float* out = (float*)d_out;

    float* kT = (float*)d_ws;          // (B, D, T)
    float* vT = kT + MM * DD;
    float* rT = vT + MM * DD;          // raw r (sigmoid applied in K2)
    float* yT = rT + MM * DD;          // (B, D, T) = wkv * sigmoid(r)

    gemm_mix_t<<<dim3(8, 32, 3), 256, 0, stream>>>(
        x, lx, Wk, Wv, Wr, mk, mv, mr, kT, vT, rT);

    wkv_scan<<<dim3(256), 256, 0, stream>>>(
        kT, vT, rT, x, lnum, lden, td, tf, yT, out);

    gemm_out<<<dim3(8, 32), 256, 0, stream>>>(yT, Wo, out);
}